// Round 1
// baseline (105.149 us; speedup 1.0000x reference)
//
#include <hip/hip_runtime.h>
#include <math.h>

// RotatedIoULoss: per-pair rotated-box IoU loss, mean-reduced to one f32 scalar.
// Inputs: d_in[0]=pred (n,5) f32, d_in[1]=target (n,5) f32, d_in[2]=weight (n,) f32.
// Output: d_out[0] = mean(-log(max(iou,1e-6)) * weight).
//
// R1: branchless Green's-theorem intersection (generic halfplane Liang-Barsky).
// R2: 4 boxes/thread, float4 loads, 4 independent pipelines for ILP.
// R3: exploit rectangle structure — clip each box's edges against the OTHER
//     box's frame as an AABB slab clip; closed-form translation correction.
//     ~330 VALU-equiv/box.
// R4: occupancy/latency attack — 2 boxes/thread (was 4). Halves live VGPR
//     state (44 input floats + 4 pipelines -> 22 + 2), doubles grid to
//     1954 blocks (7.6/CU, smaller tail). Target: VGPR ~90 -> 5 waves/SIMD
//     vs ~3; ILP-2 x 5 waves covers the 4-6 cyc VALU dep chains. Loads
//     become float2 (8B-aligned at 40B/thread stride) — still coalesced
//     across the wave.

__device__ __forceinline__ float rcpf(float x) { return __builtin_amdgcn_rcpf(x); }

// Clip one edge (start (u0,v0), direction (dx,dy), reciprocal dir (rx,ry))
// against the AABB [-hw,hw]x[-hh,hh]; accumulate Green cross term and (if
// TRACK) the net displacement of the valid piece.
template <bool TRACK>
__device__ __forceinline__ void clip_edge(float u0, float v0, float dx, float dy,
                                          float rx, float ry, float hw, float hh,
                                          float& S, float& Dx, float& Dy)
{
    float ta = (-hw - u0) * rx;
    float tb = ( hw - u0) * rx;
    float tc = (-hh - v0) * ry;
    float td = ( hh - v0) * ry;
    float tumin = fminf(ta, tb), tumax = fmaxf(ta, tb);
    float tvmin = fminf(tc, td), tvmax = fmaxf(tc, td);
    float t0 = fmaxf(fmaxf(tumin, tvmin), 0.0f);   // v_max3
    float t1 = fminf(fminf(tumax, tvmax), 1.0f);   // v_min3
    bool valid = t1 > t0;
    float sx = fmaf(t0, dx, u0), sy = fmaf(t0, dy, v0);
    float ex = fmaf(t1, dx, u0), ey = fmaf(t1, dy, v0);
    float c = sx * ey - sy * ex;
    S += valid ? c : 0.0f;
    if (TRACK) {
        Dx += valid ? (ex - sx) : 0.0f;
        Dy += valid ? (ey - sy) : 0.0f;
    }
}

// Quad with CCW corners (+U+V, -U+V, -U-V, +U-V) + c, clipped to AABB(hw,hh).
// Edge vectors are (-2U, -2V, +2U, +2V) -> only 4 distinct rcps.
template <bool TRACK>
__device__ __forceinline__ float clip_quad(float Ux, float Uy, float Vx, float Vy,
                                           float cx, float cy, float hw, float hh,
                                           float& Dx, float& Dy)
{
    float d0x = -2.0f * Ux, d0y = -2.0f * Uy;   // edge 0 and (negated) edge 2
    float d1x = -2.0f * Vx, d1y = -2.0f * Vy;   // edge 1 and (negated) edge 3
    float r0x = rcpf(d0x), r0y = rcpf(d0y);
    float r1x = rcpf(d1x), r1y = rcpf(d1y);

    float sxv = Ux + Vx, syv = Uy + Vy;   // c0 offset
    float dxv = Ux - Vx, dyv = Uy - Vy;   // c3 offset

    float S = 0.0f;
    // c0 = ( sx, sy)+c, d0
    clip_edge<TRACK>( sxv + cx,  syv + cy,  d0x,  d0y,  r0x,  r0y, hw, hh, S, Dx, Dy);
    // c1 = (-dx,-dy)+c, d1
    clip_edge<TRACK>(-dxv + cx, -dyv + cy,  d1x,  d1y,  r1x,  r1y, hw, hh, S, Dx, Dy);
    // c2 = (-sx,-sy)+c, -d0
    clip_edge<TRACK>(-sxv + cx, -syv + cy, -d0x, -d0y, -r0x, -r0y, hw, hh, S, Dx, Dy);
    // c3 = ( dx, dy)+c, -d1
    clip_edge<TRACK>( dxv + cx,  dyv + cy, -d1x, -d1y, -r1x, -r1y, hw, hh, S, Dx, Dy);
    return S;
}

__device__ __forceinline__ float riou_one(float px, float py, float pw, float ph, float pa,
                                          float qx, float qy, float qw, float qh, float qa,
                                          float w)
{
    float hw1 = 0.5f * pw, hh1 = 0.5f * ph;
    float hw2 = 0.5f * qw, hh2 = 0.5f * qh;

    float ca = __cosf(pa), sa = __sinf(pa);
    float delta = pa - qa;
    float cr = __cosf(delta), sr = __sinf(delta);

    float ox = qx - px, oy = qy - py;          // q - p in world frame
    // Q center in P-frame: R(-pa) * o
    float cPx =  ca * ox + sa * oy;
    float cPy = -sa * ox + ca * oy;
    // P center in Q-frame: cQ = -R_PQ * cP, R_PQ = [cr -sr; sr cr]
    float cQx = -(cr * cPx - sr * cPy);
    float cQy = -(sr * cPx + cr * cPy);

    // Set A: P's quad in Q-frame, clip box (hw2,hh2).
    //   U = R_PQ*(hw1,0) = (cr*hw1, sr*hw1); V = R_PQ*(0,hh1) = (-sr*hh1, cr*hh1)
    float dum0 = 0.0f, dum1 = 0.0f;
    float SA = clip_quad<false>(cr * hw1, sr * hw1, -sr * hh1, cr * hh1,
                                cQx, cQy, hw2, hh2, dum0, dum1);

    // Set B: Q's quad in P-frame, clip box (hw1,hh1). Track D for the
    // frame-translation correction.
    //   U = R_QP*(hw2,0) = (cr*hw2, -sr*hw2); V = R_QP*(0,hh2) = (sr*hh2, cr*hh2)
    float Dx = 0.0f, Dy = 0.0f;
    float SB = clip_quad<true>(cr * hw2, -sr * hw2, sr * hh2, cr * hh2,
                               cPx, cPy, hw1, hh1, Dx, Dy);

    // corr = cross(cQ, R_PQ * D)
    float RDx = cr * Dx - sr * Dy;
    float RDy = sr * Dx + cr * Dy;
    float corr = cQx * RDy - cQy * RDx;

    float inter = fmaxf(0.5f * (SA + SB + corr), 0.0f);
    float a1 = pw * ph;
    float a2 = qw * qh;
    float iou = inter * rcpf(a1 + a2 - inter);
    iou = fmaxf(iou, 1e-6f);
    return -__logf(iou) * w;
}

__global__ void __launch_bounds__(256)
riou_loss_kernel(const float* __restrict__ pred,
                 const float* __restrict__ target,
                 const float* __restrict__ weight,
                 float* __restrict__ out,
                 int n, float inv_n)
{
    int t = blockIdx.x * blockDim.x + threadIdx.x;
    int base = t * 2;
    float loss = 0.0f;

    if (base < n) {
        float pp[10], qq[10], ww[2];
        if (base + 2 <= n) {
            // 40 B per thread per array, 8B-aligned: five float2 loads each
            const float2* P2 = (const float2*)(pred   + (size_t)base * 5);
            const float2* Q2 = (const float2*)(target + (size_t)base * 5);
            #pragma unroll
            for (int i = 0; i < 5; i++) {
                float2 p = P2[i];
                pp[2 * i + 0] = p.x; pp[2 * i + 1] = p.y;
                float2 q = Q2[i];
                qq[2 * i + 0] = q.x; qq[2 * i + 1] = q.y;
            }
            float2 w2 = ((const float2*)weight)[t];
            ww[0] = w2.x; ww[1] = w2.y;
        } else {
            // base == n-1: one real box; duplicate it into slot 1 with w=0
            #pragma unroll
            for (int j = 0; j < 5; j++) {
                pp[j] = pred[(size_t)base * 5 + j];
                qq[j] = target[(size_t)base * 5 + j];
                pp[5 + j] = pp[j];
                qq[5 + j] = qq[j];
            }
            ww[0] = weight[base];
            ww[1] = 0.0f;
        }

        #pragma unroll
        for (int k = 0; k < 2; k++) {
            loss += riou_one(pp[5 * k + 0], pp[5 * k + 1], pp[5 * k + 2],
                             pp[5 * k + 3], pp[5 * k + 4],
                             qq[5 * k + 0], qq[5 * k + 1], qq[5 * k + 2],
                             qq[5 * k + 3], qq[5 * k + 4],
                             ww[k]);
        }
    }

    // block reduction: wave shuffle (width 64) -> LDS -> one atomic per block
    #pragma unroll
    for (int off = 32; off > 0; off >>= 1)
        loss += __shfl_down(loss, off, 64);

    __shared__ float ssum[4];
    int wave = threadIdx.x >> 6;
    int lane = threadIdx.x & 63;
    if (lane == 0) ssum[wave] = loss;
    __syncthreads();
    if (threadIdx.x == 0) {
        float s = ssum[0] + ssum[1] + ssum[2] + ssum[3];
        atomicAdd(out, s * inv_n);
    }
}

extern "C" void kernel_launch(void* const* d_in, const int* in_sizes, int n_in,
                              void* d_out, int out_size, void* d_ws, size_t ws_size,
                              hipStream_t stream) {
    const float* pred   = (const float*)d_in[0];
    const float* target = (const float*)d_in[1];
    const float* weight = (const float*)d_in[2];
    float* out = (float*)d_out;

    int n = in_sizes[0] / 5;

    // d_out is poisoned to 0xAA before every timed launch -> zero it ourselves.
    hipMemsetAsync(out, 0, sizeof(float), stream);

    int block = 256;
    int threads_needed = (n + 1) / 2;
    int grid = (threads_needed + block - 1) / block;
    riou_loss_kernel<<<grid, block, 0, stream>>>(pred, target, weight, out,
                                                 n, 1.0f / (float)n);
}